// Round 6
// baseline (223.215 us; speedup 1.0000x reference)
//
#include <hip/hip_runtime.h>
#include <cmath>

typedef unsigned int uint;
typedef unsigned long long ull;

#define BATCH 32
#define NA 8400
#define NC 80
#define MAXDET 100
#define NMSTHR 0.65f
#define SCTHR 0.01f

#define NT 1024         // NMS threads per block
#define NW (NT / 64)
#define EPT 9           // ceil(NA / NT)
#define NBINS 4096      // histogram bins on key[31:20]
#define CAP 512         // max candidates per sorted window

__device__ __forceinline__ float stable_sigmoid(float x) {
    if (x >= 0.f) return 1.f / (1.f + expf(-x));
    float e = expf(x);
    return e / (1.f + e);
}

// ---------------- decode: FOUR threads per anchor (r0-EXACT, DO NOT TOUCH) ----
// Sub-thread q scans channels [20q, 20q+20): 20 independent loads batched
// into registers (deep memory-level parallelism), then a 4-lane shfl
// butterfly merges (max, lowest-channel) -> exact jnp.argmax semantics.
// NOTE: r4 added a return value + hist/amax atomics to this function and the
// compiler collapsed the allocation to 20 VGPRs, serializing the 20 loads
// (176 us vs <54 us). Keep this function tail-free and store-only.
template<int HW, int W, int S>
__device__ __forceinline__ void decode4(
    const float* __restrict__ cls, const float* __restrict__ reg,
    const float* __restrict__ obj, int b, int p, int q, int ag,
    float4* __restrict__ wboxes, int* __restrict__ wlabels, uint* __restrict__ wkeys)
{
    const float* cbase = cls + (size_t)b * NC * HW + (size_t)(q * 20) * HW + p;
    float v[20];
    #pragma unroll
    for (int i = 0; i < 20; ++i) v[i] = cbase[(size_t)i * HW];
    float m = v[0]; int c = 0;
    #pragma unroll
    for (int i = 1; i < 20; ++i)
        if (v[i] > m) { m = v[i]; c = i; }     // strict > -> first max in slice
    c += q * 20;

    // merge the 4 sub-threads (lanes 4k..4k+3): tie -> lower channel index
    #pragma unroll
    for (int o = 1; o <= 2; o <<= 1) {
        float om = __shfl_xor(m, o);
        int   oc = __shfl_xor(c, o);
        if (om > m || (om == m && oc < c)) { m = om; c = oc; }
    }

    if (q == 0) {
        const float* rb = reg + (size_t)b * 4 * HW + p;
        float r0 = rb[0];
        float r1 = rb[HW];
        float r2 = rb[2 * (size_t)HW];
        float r3 = rb[3 * (size_t)HW];
        float ov = obj[(size_t)b * HW + p];

        int y = p / W;            // W constexpr -> magic mul
        int x = p - y * W;
        float sc = stable_sigmoid(m) * stable_sigmoid(ov);
        float cx = r0 * (float)S + (float)x * (float)S;
        float cy = r1 * (float)S + (float)y * (float)S;
        float bw = expf(r2) * (float)S;
        float bh = expf(r3) * (float)S;

        wboxes[ag]  = make_float4(cx - bw * 0.5f, cy - bh * 0.5f,
                                  cx + bw * 0.5f, cy + bh * 0.5f);
        wlabels[ag] = c;
        wkeys[ag]   = (sc >= SCTHR) ? ~__float_as_uint(sc) : 0xFFFFFFFFu;
    }
}

__global__ __launch_bounds__(256) void decode_kernel(
    const float* __restrict__ cls0, const float* __restrict__ reg0, const float* __restrict__ obj0,
    const float* __restrict__ cls1, const float* __restrict__ reg1, const float* __restrict__ obj1,
    const float* __restrict__ cls2, const float* __restrict__ reg2, const float* __restrict__ obj2,
    float4* __restrict__ wboxes, int* __restrict__ wlabels, uint* __restrict__ wkeys)
{
    int gid = blockIdx.x * blockDim.x + threadIdx.x;   // BATCH*NA*4 threads exactly
    int ag = gid >> 2;       // global anchor id
    int q  = gid & 3;        // channel-slice id
    int b = ag / NA;
    int j = ag - b * NA;

    if (j < 6400)
        decode4<6400, 80, 8>(cls0, reg0, obj0, b, j, q, ag, wboxes, wlabels, wkeys);
    else if (j < 8000)
        decode4<1600, 40, 16>(cls1, reg1, obj1, b, j - 6400, q, ag, wboxes, wlabels, wkeys);
    else
        decode4<400, 20, 32>(cls2, reg2, obj2, b, j - 8000, q, ag, wboxes, wlabels, wkeys);
}

// ---------------- NMS via sorted walk + precomputed suppression bitmask ----
// vs r5 (48.5 us): (1) amax sweep fused into hist sweep (one fewer 9-iter
// global pass); (2) after sort+prefetch, ALL 16 waves build the upper-
// triangle pairwise-suppression bitmask in parallel (ballot per 64-column
// block), so the serial wave-0 walk is just find-first-set + AND-NOT over
// a 512-bit alive vector (~20 instr per kept vs ~40+IoU loop). Sorted
// order guarantees the picked index is the MINIMUM alive index, so j<i
// bits are never consulted -> triangle mask suffices and stale low-block
// garbage is harmless. Cross-window exactness: candidates of window w>0
// are pre-suppressed in parallel against kept boxes of earlier windows.
// The mask (32 KB) aliases the dead histogram region.
__global__ __launch_bounds__(NT) void nms_kernel(
    const float4* __restrict__ wboxes, const int* __restrict__ wlabels,
    const uint* __restrict__ wkeys, float* __restrict__ out)
{
    int b = blockIdx.x;
    int t = threadIdx.x;
    int lane = t & 63;
    int wv = t >> 6;
    const float4* boxes  = wboxes  + (size_t)b * NA;
    const int*    labels = wlabels + (size_t)b * NA;
    const uint*   keys   = wkeys   + (size_t)b * NA;

    __shared__ ull    s_mask[CAP][8];      // 32 KB; aliases s_hist (16 KB)
    __shared__ uint   s_cum[NBINS + 1];    // exclusive prefix
    __shared__ ull    s_skey[CAP];
    __shared__ float4 s_cbox[CAP];         // candidate OFFSET boxes (prefetched)
    __shared__ float  s_kbox[MAXDET][4];   // kept OFFSET boxes (cross-window)
    __shared__ int    s_kidx[MAXDET];      // kept anchor ids
    __shared__ float  s_kscr[MAXDET];      // kept scores
    __shared__ int    s_kci[MAXDET];       // kept candidate slot (this window)
    __shared__ ull    s_alive[8];
    __shared__ uint   s_wsum[NW];
    __shared__ float  s_red[NW];
    __shared__ float  s_off;
    __shared__ int    s_kept, s_winlo, s_winhi, s_nsel;

    uint* s_hist = reinterpret_cast<uint*>(&s_mask[0][0]);

    // ---- zero hist; fused sweep: max|coord| + key histogram ----
    for (int i = t; i < NBINS; i += NT) s_hist[i] = 0;
    if (t == 0) { s_kept = 0; s_winlo = 0; }
    __syncthreads();
    float m = 0.f;
    #pragma unroll
    for (int w = 0; w < EPT; ++w) {
        int e = t + w * NT;
        if (e < NA) {
            float4 v = boxes[e];
            m = fmaxf(m, fmaxf(fmaxf(fabsf(v.x), fabsf(v.y)),
                               fmaxf(fabsf(v.z), fabsf(v.w))));
            uint k = keys[e];
            if (k != 0xFFFFFFFFu) atomicAdd(&s_hist[k >> 20], 1u);
        }
    }
    #pragma unroll
    for (int o = 32; o >= 1; o >>= 1) m = fmaxf(m, __shfl_xor(m, o));
    if (lane == 0) s_red[wv] = m;
    __syncthreads();
    if (t == 0) {
        float mm = 0.f;
        for (int w = 0; w < NW; ++w) mm = fmaxf(mm, s_red[w]);
        s_off = mm + 1.f;
    }

    // ---- exclusive scan over 4096 bins: 4 bins/thread + shfl scans ----
    uint l0 = s_hist[4 * t], l1 = s_hist[4 * t + 1],
         l2 = s_hist[4 * t + 2], l3 = s_hist[4 * t + 3];
    uint L = l0 + l1 + l2 + l3;
    uint ls = L;
    #pragma unroll
    for (int o = 1; o < 64; o <<= 1) {
        uint v = __shfl_up(ls, o);
        if (lane >= o) ls += v;
    }
    if (lane == 63) s_wsum[wv] = ls;
    __syncthreads();
    if (t < NW) {
        uint v = s_wsum[t];
        uint vs = v;
        #pragma unroll
        for (int o = 1; o < NW; o <<= 1) {
            uint u = __shfl_up(vs, o);
            if ((t & 63) >= o) vs += u;
        }
        s_wsum[t] = vs - v;
    }
    __syncthreads();
    uint base = s_wsum[wv] + (ls - L);
    s_cum[4 * t]     = base;
    s_cum[4 * t + 1] = base + l0;
    s_cum[4 * t + 2] = base + l0 + l1;
    s_cum[4 * t + 3] = base + l0 + l1 + l2;
    if (t == NT - 1) s_cum[NBINS] = base + L;

    // ---- window loop (typically runs once) ----
    for (;;) {
        __syncthreads();
        int kept = s_kept, winlo = s_winlo;
        uint remaining = s_cum[NBINS] - s_cum[winlo];
        if (kept >= MAXDET || winlo >= NBINS || remaining == 0u) break;
        if (t == 0) { s_winhi = winlo + 1; s_nsel = 0; }   // giant-bin clamp floor
        if (t < CAP) s_skey[t] = ~0ull;
        __syncthreads();
        // winhi via unique-boundary store: pred(i) = cum[i+1]-cl <= CAP is
        // monotone non-increasing in i, so exactly one i has pred(i) && !pred(i+1).
        uint cl = s_cum[winlo];
        #pragma unroll
        for (int q = 0; q < 4; ++q) {
            int i = t + q * NT;
            if (i >= winlo && i < NBINS) {
                bool p0 = (s_cum[i + 1] - cl) <= (uint)CAP;
                bool p1 = (i + 1 < NBINS) && ((s_cum[i + 2] - cl) <= (uint)CAP);
                if (p0 && !p1) s_winhi = i + 1;   // unique writer
            }
        }
        __syncthreads();
        int winhi = s_winhi;

        // wave-aggregated compaction of window candidates (keys from global, L2-hot)
        #pragma unroll
        for (int w = 0; w < EPT; ++w) {
            int e = t + w * NT;
            bool q = false;
            uint k = 0;
            if (e < NA) {
                k = keys[e];
                if (k != 0xFFFFFFFFu) {
                    int bin = (int)(k >> 20);
                    q = (bin >= winlo && bin < winhi);
                }
            }
            ull mask = __ballot(q);
            if (mask) {
                int leader = __ffsll(mask) - 1;
                int pbase = 0;
                if (lane == leader) pbase = atomicAdd(&s_nsel, __popcll(mask));
                pbase = __shfl(pbase, leader);
                if (q) {
                    int pos = pbase + __popcll(mask & ((1ull << lane) - 1ull));
                    if (pos < CAP) s_skey[pos] = ((ull)k << 32) | (uint)e;
                }
            }
        }
        __syncthreads();
        int nsel = s_nsel; if (nsel > CAP) nsel = CAP;

        // hybrid bitonic sort of CAP=512 ull keys ascending: j<64 passes are
        // intra-wave shfl_xor (no barrier); j>=64 via LDS (6 barriered passes).
        ull k = (t < CAP) ? s_skey[t] : ~0ull;
        for (int k2 = 2; k2 <= CAP; k2 <<= 1) {
            for (int j = k2 >> 1; j > 0; j >>= 1) {
                if (j >= 64) {
                    if (t < CAP) s_skey[t] = k;
                    __syncthreads();
                    if (t < CAP) {
                        ull kp = s_skey[t ^ j];
                        bool low = (t & j) == 0;
                        bool up  = (t & k2) == 0;
                        k = ((k < kp) == (low == up)) ? k : kp;
                    }
                    __syncthreads();
                } else if (t < CAP) {
                    ull kp = __shfl_xor(k, j);
                    bool low = (t & j) == 0;
                    bool up  = (t & k2) == 0;
                    k = ((k < kp) == (low == up)) ? k : kp;
                }
            }
        }
        if (t < CAP) s_skey[t] = k;
        __syncthreads();

        // parallel candidate prefetch: scattered global reads done ONCE by
        // all threads; everything below touches only LDS.
        float off = s_off;
        if (t < nsel) {
            ull sk = s_skey[t];
            int idx = (int)(sk & 0xFFFFFFFFull);
            float4 rb = boxes[idx];
            float lo = (float)labels[idx] * off;
            s_cbox[t] = make_float4(rb.x + lo, rb.y + lo, rb.z + lo, rb.w + lo);
        }
        __syncthreads();

        int kprev = s_kept;

        // ---- parallel alive init: suppress vs kept boxes of PRIOR windows ----
        bool al = false;
        if (t < nsel) {
            al = true;
            float4 bt = s_cbox[t];
            float at = (bt.z - bt.x) * (bt.w - bt.y);
            for (int q = 0; q < kprev; ++q) {
                float k0 = s_kbox[q][0], k1 = s_kbox[q][1];
                float k2c = s_kbox[q][2], k3 = s_kbox[q][3];
                float ak = (k2c - k0) * (k3 - k1);
                float tlx = fmaxf(k0, bt.x), tly = fmaxf(k1, bt.y);
                float brx = fminf(k2c, bt.z), bry = fminf(k3, bt.w);
                float ww = fmaxf(brx - tlx, 0.f), hh = fmaxf(bry - tly, 0.f);
                float inter = ww * hh;
                float iou = inter / (ak + at - inter + 1e-6f);
                if (iou > NMSTHR) { al = false; break; }
            }
        }
        if (wv < 8) {
            ull bm = __ballot(al);
            if (lane == 0) s_alive[wv] = bm;
        }

        // ---- parallel upper-triangle suppression mask build ----
        // wave wv handles rows i = wv, wv+16, ... ; 64 columns per ballot.
        for (int i = wv; i < nsel; i += NW) {
            float4 bi = s_cbox[i];
            float ai = (bi.z - bi.x) * (bi.w - bi.y);
            int cb0 = i >> 6;
            for (int cblk = cb0; cblk < 8; ++cblk) {
                int j = (cblk << 6) + lane;
                bool sup = false;
                if (j > i && j < nsel) {
                    float4 bj = s_cbox[j];
                    float aj = (bj.z - bj.x) * (bj.w - bj.y);
                    float tlx = fmaxf(bi.x, bj.x), tly = fmaxf(bi.y, bj.y);
                    float brx = fminf(bi.z, bj.z), bry = fminf(bi.w, bj.w);
                    float ww = fmaxf(brx - tlx, 0.f), hh = fmaxf(bry - tly, 0.f);
                    float inter = ww * hh;
                    float iou = inter / (ai + aj - inter + 1e-6f);
                    sup = iou > NMSTHR;
                }
                ull bm = __ballot(sup);
                if (lane == 0) s_mask[i][cblk] = bm;
            }
        }
        __syncthreads();

        // ---- serial walk on wave 0: find-first-set + AND-NOT ----
        if (t < 64) {
            int kept2 = s_kept;
            ull alive = (lane < 8) ? s_alive[lane] : 0ull;
            while (kept2 < MAXDET) {
                int pos = (alive != 0ull) ? ((lane << 6) + __ffsll(alive) - 1)
                                          : 0x7FFFFFFF;
                #pragma unroll
                for (int o = 1; o <= 32; o <<= 1) {
                    int op = __shfl_xor(pos, o);
                    pos = (op < pos) ? op : pos;
                }
                if (pos == 0x7FFFFFFF) break;
                int i = pos;                       // uniform across wave
                if (lane == 0) {
                    ull sk = s_skey[i];
                    s_kidx[kept2] = (int)(sk & 0xFFFFFFFFull);
                    s_kscr[kept2] = __uint_as_float(~(uint)(sk >> 32));
                    s_kci[kept2]  = i;
                }
                if (lane < 8) {
                    alive &= ~s_mask[i][lane];
                    if ((i >> 6) == lane) alive &= ~(1ull << (i & 63));
                }
                kept2++;
            }
            if (lane == 0) s_kept = kept2;
        }
        __syncthreads();

        // ---- save this window's kept boxes for cross-window suppression ----
        {
            int kept2 = s_kept;
            if (t >= kprev && t < kept2) {
                float4 cb = s_cbox[s_kci[t]];
                s_kbox[t][0] = cb.x; s_kbox[t][1] = cb.y;
                s_kbox[t][2] = cb.z; s_kbox[t][3] = cb.w;
            }
        }
        if (t == 0) s_winlo = winhi;
    }
    __syncthreads();

    // ---- epilogue: boxes/scores/labels/valid (fp32) ----
    if (t < MAXDET) {
        int kept = s_kept;
        float4 obx = make_float4(0.f, 0.f, 0.f, 0.f);
        float osc = 0.f, olab = -1.f, oval = 0.f;
        if (t < kept) {
            int idx = s_kidx[t];
            obx  = boxes[idx];              // raw (non-offset) box
            osc  = s_kscr[t];
            olab = (float)labels[idx];
            oval = 1.f;
        }
        float* ob = out + ((size_t)b * MAXDET + t) * 4;
        ob[0] = obx.x; ob[1] = obx.y; ob[2] = obx.z; ob[3] = obx.w;
        out[BATCH * MAXDET * 4 + b * MAXDET + t] = osc;
        out[BATCH * MAXDET * 5 + b * MAXDET + t] = olab;
        out[BATCH * MAXDET * 6 + b * MAXDET + t] = oval;
    }
}

extern "C" void kernel_launch(void* const* d_in, const int* in_sizes, int n_in,
                              void* d_out, int out_size, void* d_ws, size_t ws_size,
                              hipStream_t stream) {
    // setup_inputs() dict order: cls0, reg0, obj0, cls1, reg1, obj1, cls2, reg2, obj2
    const float* cls0 = (const float*)d_in[0];
    const float* reg0 = (const float*)d_in[1];
    const float* obj0 = (const float*)d_in[2];
    const float* cls1 = (const float*)d_in[3];
    const float* reg1 = (const float*)d_in[4];
    const float* obj1 = (const float*)d_in[5];
    const float* cls2 = (const float*)d_in[6];
    const float* reg2 = (const float*)d_in[7];
    const float* obj2 = (const float*)d_in[8];

    // ws layout: boxes | labels | keys
    char* ws = (char*)d_ws;
    size_t nBA = (size_t)BATCH * NA;
    float4* wboxes  = (float4*)ws;
    int*    wlabels = (int*)(ws + nBA * 16);
    uint*   wkeys   = (uint*)(ws + nBA * 20);

    int total = BATCH * NA * 4;   // 1,075,200 = 4200 * 256 exactly
    decode_kernel<<<total / 256, 256, 0, stream>>>(
        cls0, reg0, obj0, cls1, reg1, obj1, cls2, reg2, obj2,
        wboxes, wlabels, wkeys);

    nms_kernel<<<BATCH, NT, 0, stream>>>(wboxes, wlabels, wkeys, (float*)d_out);
}

// Round 7
// 166.441 us; speedup vs baseline: 1.3411x; 1.3411x over previous
//
#include <hip/hip_runtime.h>
#include <cmath>

typedef unsigned int uint;
typedef unsigned long long ull;

#define BATCH 32
#define NA 8400
#define NC 80
#define MAXDET 100
#define NMSTHR 0.65f
#define SCTHR 0.01f

#define NT 1024         // NMS threads per block
#define NW (NT / 64)
#define EPT 9           // ceil(NA / NT)
#define NBINS 4096      // histogram bins on key[31:20]
#define CAP 512         // max candidates per sorted window

#define DGROUPS 132     // 64-anchor groups per image: 100 (L0) + 25 (L1) + 7 (L2)

__device__ __forceinline__ float stable_sigmoid(float x) {
    if (x >= 0.f) return 1.f / (1.f + expf(-x));
    float e = expf(x);
    return e / (1.f + e);
}

// ---------------- decode: one 256-thread block per 64 anchors ----------------
// Wave w scans channels [20w, 20w+20) for the block's 64 consecutive anchors:
// every load is uniform-base + lane*4 -> ONE 256B contiguous segment per wave
// instruction (r0's proven pattern issued 4 x 64B segments per instruction).
// Same total wave count as r0 (16,896) and same instruction count; only the
// segment count per instruction changes. Per-wave (max, argmax) in registers
// with strict '>' (first max); 2KB LDS merge in ascending wave order (tie ->
// lower wave -> lower channel) -> exact jnp.argmax semantics. Wave 0 runs the
// reg/obj/box epilogue with unit-stride loads/stores. No atomics, no function
// tails (r4's regalloc-collapse lesson), no store->reload (r3's lesson).
template<int HW, int W, int S>
__device__ __forceinline__ void decode_blk(
    const float* __restrict__ cls, const float* __restrict__ reg,
    const float* __restrict__ obj, int b, int p0, int w, int lane, int ag0,
    float (*s_m)[64], int (*s_c)[64],
    float4* __restrict__ wboxes, int* __restrict__ wlabels, uint* __restrict__ wkeys)
{
    int p = p0 + lane;
    bool valid = (p < HW);            // only the last L2 group has invalid lanes
    int pc = valid ? p : (HW - 1);    // clamped for safe (dup) loads

    const float* cbase = cls + (size_t)b * NC * HW + (size_t)(w * 20) * HW + pc;
    float v[20];
    #pragma unroll
    for (int i = 0; i < 20; ++i) v[i] = cbase[(size_t)i * HW];
    float m = v[0]; int c = 0;
    #pragma unroll
    for (int i = 1; i < 20; ++i)
        if (v[i] > m) { m = v[i]; c = i; }     // strict > -> first max in slice

    s_m[w][lane] = m;
    s_c[w][lane] = c + w * 20;
    __syncthreads();

    if (w == 0) {
        float mm = s_m[0][lane]; int cc = s_c[0][lane];
        #pragma unroll
        for (int ww = 1; ww < 4; ++ww) {
            float om = s_m[ww][lane]; int oc = s_c[ww][lane];
            if (om > mm) { mm = om; cc = oc; } // strict > keeps lowest channel
        }
        const float* rb = reg + (size_t)b * 4 * HW + pc;
        float r0 = rb[0];
        float r1 = rb[HW];
        float r2 = rb[2 * (size_t)HW];
        float r3 = rb[3 * (size_t)HW];
        float ov = obj[(size_t)b * HW + pc];

        int y = pc / W;               // W constexpr -> magic mul
        int x = pc - y * W;
        float sc = stable_sigmoid(mm) * stable_sigmoid(ov);
        float cx = r0 * (float)S + (float)x * (float)S;
        float cy = r1 * (float)S + (float)y * (float)S;
        float bw = expf(r2) * (float)S;
        float bh = expf(r3) * (float)S;

        if (valid) {
            int ag = ag0 + lane;
            wboxes[ag]  = make_float4(cx - bw * 0.5f, cy - bh * 0.5f,
                                      cx + bw * 0.5f, cy + bh * 0.5f);
            wlabels[ag] = cc;
            wkeys[ag]   = (sc >= SCTHR) ? ~__float_as_uint(sc) : 0xFFFFFFFFu;
        }
    }
}

__global__ __launch_bounds__(256) void decode_kernel(
    const float* __restrict__ cls0, const float* __restrict__ reg0, const float* __restrict__ obj0,
    const float* __restrict__ cls1, const float* __restrict__ reg1, const float* __restrict__ obj1,
    const float* __restrict__ cls2, const float* __restrict__ reg2, const float* __restrict__ obj2,
    float4* __restrict__ wboxes, int* __restrict__ wlabels, uint* __restrict__ wkeys)
{
    __shared__ float s_m[4][64];
    __shared__ int   s_c[4][64];

    int bid  = blockIdx.x;            // BATCH * DGROUPS blocks
    int b    = bid / DGROUPS;         // literal divisor -> magic mul
    int g    = bid - b * DGROUPS;
    int t    = threadIdx.x;
    int w    = t >> 6;
    int lane = t & 63;

    if (g < 100) {
        int p0 = g * 64;
        decode_blk<6400, 80, 8>(cls0, reg0, obj0, b, p0, w, lane,
                                b * NA + p0, s_m, s_c, wboxes, wlabels, wkeys);
    } else if (g < 125) {
        int p0 = (g - 100) * 64;
        decode_blk<1600, 40, 16>(cls1, reg1, obj1, b, p0, w, lane,
                                 b * NA + 6400 + p0, s_m, s_c, wboxes, wlabels, wkeys);
    } else {
        int p0 = (g - 125) * 64;
        decode_blk<400, 20, 32>(cls2, reg2, obj2, b, p0, w, lane,
                                b * NA + 8000 + p0, s_m, s_c, wboxes, wlabels, wkeys);
    }
}

// ---------------- NMS via sorted walk (r5-EXACT, measured 48.6 us) ----------
__global__ __launch_bounds__(NT) void nms_kernel(
    const float4* __restrict__ wboxes, const int* __restrict__ wlabels,
    const uint* __restrict__ wkeys, float* __restrict__ out)
{
    int b = blockIdx.x;
    int t = threadIdx.x;
    int lane = t & 63;
    int wv = t >> 6;
    const float4* boxes  = wboxes  + (size_t)b * NA;
    const int*    labels = wlabels + (size_t)b * NA;
    const uint*   keys   = wkeys   + (size_t)b * NA;

    __shared__ uint   s_hist[NBINS];
    __shared__ uint   s_cum[NBINS + 1];    // exclusive prefix
    __shared__ uint   s_wsum[NW];
    __shared__ ull    s_skey[CAP];
    __shared__ float4 s_cbox[CAP];         // candidate OFFSET boxes (prefetched)
    __shared__ float  s_ca[CAP];           // candidate offset-box areas
    __shared__ int    s_clb[CAP];          // candidate labels
    __shared__ float  s_kbox[MAXDET][4];   // kept OFFSET boxes
    __shared__ float  s_ka1[MAXDET];
    __shared__ int    s_kidx[MAXDET];
    __shared__ float  s_kscr[MAXDET];
    __shared__ int    s_klab[MAXDET];
    __shared__ float  s_red[NW];
    __shared__ float  s_off;
    __shared__ int    s_kept, s_winlo, s_winhi, s_nsel;

    // ---- offset = max|coord| over ALL boxes + 1 (boxes are L2/L3-hot) ----
    float m = 0.f;
    #pragma unroll
    for (int w = 0; w < EPT; ++w) {
        int e = t + w * NT;
        if (e < NA) {
            float4 v = boxes[e];
            m = fmaxf(m, fmaxf(fmaxf(fabsf(v.x), fabsf(v.y)),
                               fmaxf(fabsf(v.z), fabsf(v.w))));
        }
    }
    #pragma unroll
    for (int o = 32; o >= 1; o >>= 1) m = fmaxf(m, __shfl_xor(m, o));
    if (lane == 0) s_red[wv] = m;
    // ---- LDS histogram of precomputed keys ----
    for (int i = t; i < NBINS; i += NT) s_hist[i] = 0;
    if (t == 0) { s_kept = 0; s_winlo = 0; }
    __syncthreads();
    if (t == 0) {
        float mm = 0.f;
        for (int w = 0; w < NW; ++w) mm = fmaxf(mm, s_red[w]);
        s_off = mm + 1.f;
    }
    #pragma unroll
    for (int w = 0; w < EPT; ++w) {
        int e = t + w * NT;
        if (e < NA) {
            uint k = keys[e];
            if (k != 0xFFFFFFFFu) atomicAdd(&s_hist[k >> 20], 1u);
        }
    }
    __syncthreads();
    float off = s_off;

    // ---- exclusive scan over 4096 bins: 4 bins/thread + shfl scans ----
    uint l0 = s_hist[4 * t], l1 = s_hist[4 * t + 1],
         l2 = s_hist[4 * t + 2], l3 = s_hist[4 * t + 3];
    uint L = l0 + l1 + l2 + l3;
    uint ls = L;
    #pragma unroll
    for (int o = 1; o < 64; o <<= 1) {
        uint v = __shfl_up(ls, o);
        if (lane >= o) ls += v;
    }
    if (lane == 63) s_wsum[wv] = ls;
    __syncthreads();
    if (t < NW) {
        uint v = s_wsum[t];
        uint vs = v;
        #pragma unroll
        for (int o = 1; o < NW; o <<= 1) {
            uint u = __shfl_up(vs, o);
            if ((t & 63) >= o) vs += u;
        }
        s_wsum[t] = vs - v;
    }
    __syncthreads();
    uint base = s_wsum[wv] + (ls - L);
    s_cum[4 * t]     = base;
    s_cum[4 * t + 1] = base + l0;
    s_cum[4 * t + 2] = base + l0 + l1;
    s_cum[4 * t + 3] = base + l0 + l1 + l2;
    if (t == NT - 1) s_cum[NBINS] = base + L;

    // ---- window loop (typically runs once) ----
    for (;;) {
        __syncthreads();
        int kept = s_kept, winlo = s_winlo;
        uint remaining = s_cum[NBINS] - s_cum[winlo];
        if (kept >= MAXDET || winlo >= NBINS || remaining == 0u) break;
        if (t == 0) { s_winhi = winlo + 1; s_nsel = 0; }   // giant-bin clamp floor
        if (t < CAP) s_skey[t] = ~0ull;
        __syncthreads();
        // winhi via unique-boundary store: pred(i) = cum[i+1]-cl <= CAP is
        // monotone non-increasing in i, so exactly one i has pred(i) && !pred(i+1).
        uint cl = s_cum[winlo];
        #pragma unroll
        for (int q = 0; q < 4; ++q) {
            int i = t + q * NT;
            if (i >= winlo && i < NBINS) {
                bool p0 = (s_cum[i + 1] - cl) <= (uint)CAP;
                bool p1 = (i + 1 < NBINS) && ((s_cum[i + 2] - cl) <= (uint)CAP);
                if (p0 && !p1) s_winhi = i + 1;   // unique writer
            }
        }
        __syncthreads();
        int winhi = s_winhi;

        // wave-aggregated compaction of window candidates (keys from global, L2-hot)
        #pragma unroll
        for (int w = 0; w < EPT; ++w) {
            int e = t + w * NT;
            bool q = false;
            uint k = 0;
            if (e < NA) {
                k = keys[e];
                if (k != 0xFFFFFFFFu) {
                    int bin = (int)(k >> 20);
                    q = (bin >= winlo && bin < winhi);
                }
            }
            ull mask = __ballot(q);
            if (mask) {
                int leader = __ffsll(mask) - 1;
                int pbase = 0;
                if (lane == leader) pbase = atomicAdd(&s_nsel, __popcll(mask));
                pbase = __shfl(pbase, leader);
                if (q) {
                    int pos = pbase + __popcll(mask & ((1ull << lane) - 1ull));
                    if (pos < CAP) s_skey[pos] = ((ull)k << 32) | (uint)e;
                }
            }
        }
        __syncthreads();
        int nsel = s_nsel; if (nsel > CAP) nsel = CAP;

        // hybrid bitonic sort of CAP=512 ull keys ascending: j<64 passes are
        // intra-wave shfl_xor (no barrier); j>=64 via LDS (6 barriered passes).
        ull k = (t < CAP) ? s_skey[t] : ~0ull;
        for (int k2 = 2; k2 <= CAP; k2 <<= 1) {
            for (int j = k2 >> 1; j > 0; j >>= 1) {
                if (j >= 64) {
                    if (t < CAP) s_skey[t] = k;
                    __syncthreads();
                    if (t < CAP) {
                        ull kp = s_skey[t ^ j];
                        bool low = (t & j) == 0;
                        bool up  = (t & k2) == 0;
                        k = ((k < kp) == (low == up)) ? k : kp;
                    }
                    __syncthreads();
                } else if (t < CAP) {
                    ull kp = __shfl_xor(k, j);
                    bool low = (t & j) == 0;
                    bool up  = (t & k2) == 0;
                    k = ((k < kp) == (low == up)) ? k : kp;
                }
            }
        }
        if (t < CAP) s_skey[t] = k;
        __syncthreads();

        // parallel candidate prefetch: scattered global reads done ONCE by
        // all 1024 threads; the serial walk below touches only LDS.
        if (t < nsel) {
            ull sk = s_skey[t];
            if (sk != ~0ull) {
                int idx = (int)(sk & 0xFFFFFFFFull);
                float4 rb = boxes[idx];
                int lb = labels[idx];
                float lo = (float)lb * off;
                float c0 = rb.x + lo, c1 = rb.y + lo;
                float c2 = rb.z + lo, c3 = rb.w + lo;
                s_cbox[t] = make_float4(c0, c1, c2, c3);
                s_ca[t]   = (c2 - c0) * (c3 - c1);
                s_clb[t]  = lb;
            }
        }
        __syncthreads();

        // sorted walk on wave 0 (exact reference IoU + compare)
        if (t < 64) {
            int kept2 = s_kept;
            for (int cb = 0; cb < nsel && kept2 < MAXDET; cb += 64) {
                int ci = cb + lane;
                ull sk = (ci < nsel) ? s_skey[ci] : ~0ull;
                bool has = (sk != ~0ull);
                int idx = 0, lab = 0;
                float sc = 0.f, c0 = 0.f, c1 = 0.f, c2 = 0.f, c3 = 0.f, ca = 0.f;
                if (has) {
                    idx = (int)(sk & 0xFFFFFFFFull);
                    sc  = __uint_as_float(~(uint)(sk >> 32));   // exact score bits
                    float4 cbx = s_cbox[ci];
                    c0 = cbx.x; c1 = cbx.y; c2 = cbx.z; c3 = cbx.w;
                    ca = s_ca[ci];
                    lab = s_clb[ci];
                    for (int q = 0; q < kept2; ++q) {
                        float tlx = fmaxf(s_kbox[q][0], c0);
                        float tly = fmaxf(s_kbox[q][1], c1);
                        float brx = fminf(s_kbox[q][2], c2);
                        float bry = fminf(s_kbox[q][3], c3);
                        float ww = fmaxf(brx - tlx, 0.f);
                        float hh = fmaxf(bry - tly, 0.f);
                        float inter = ww * hh;
                        float iou = inter / (s_ka1[q] + ca - inter + 1e-6f);
                        if (iou > NMSTHR) { has = false; break; }
                    }
                }
                ull am = __ballot(has);
                while (am && kept2 < MAXDET) {
                    int f = __ffsll(am) - 1;
                    float f0 = __shfl(c0, f), f1 = __shfl(c1, f);
                    float f2 = __shfl(c2, f), f3 = __shfl(c3, f);
                    float fa = __shfl(ca, f);
                    int   fidx = __shfl(idx, f);
                    int   flab = __shfl(lab, f);
                    float fsc  = __shfl(sc, f);
                    if (lane == 0) {
                        s_kbox[kept2][0] = f0; s_kbox[kept2][1] = f1;
                        s_kbox[kept2][2] = f2; s_kbox[kept2][3] = f3;
                        s_ka1[kept2] = fa; s_kidx[kept2] = fidx;
                        s_kscr[kept2] = fsc; s_klab[kept2] = flab;
                    }
                    kept2++;
                    if (lane == f) has = false;
                    if (has) {
                        float tlx = fmaxf(f0, c0), tly = fmaxf(f1, c1);
                        float brx = fminf(f2, c2), bry = fminf(f3, c3);
                        float ww = fmaxf(brx - tlx, 0.f), hh = fmaxf(bry - tly, 0.f);
                        float inter = ww * hh;
                        float iou = inter / (fa + ca - inter + 1e-6f);
                        if (iou > NMSTHR) has = false;
                    }
                    am = __ballot(has);
                }
            }
            if (lane == 0) s_kept = kept2;
        }
        __syncthreads();
        if (t == 0) s_winlo = s_winhi;
    }
    __syncthreads();

    // ---- epilogue: boxes/scores/labels/valid (fp32) ----
    if (t < MAXDET) {
        int kept = s_kept;
        float4 obx = make_float4(0.f, 0.f, 0.f, 0.f);
        float osc = 0.f, olab = -1.f, oval = 0.f;
        if (t < kept) {
            int idx = s_kidx[t];
            obx  = boxes[idx];              // raw (non-offset) box
            osc  = s_kscr[t];
            olab = (float)s_klab[t];
            oval = 1.f;
        }
        float* ob = out + ((size_t)b * MAXDET + t) * 4;
        ob[0] = obx.x; ob[1] = obx.y; ob[2] = obx.z; ob[3] = obx.w;
        out[BATCH * MAXDET * 4 + b * MAXDET + t] = osc;
        out[BATCH * MAXDET * 5 + b * MAXDET + t] = olab;
        out[BATCH * MAXDET * 6 + b * MAXDET + t] = oval;
    }
}

extern "C" void kernel_launch(void* const* d_in, const int* in_sizes, int n_in,
                              void* d_out, int out_size, void* d_ws, size_t ws_size,
                              hipStream_t stream) {
    // setup_inputs() dict order: cls0, reg0, obj0, cls1, reg1, obj1, cls2, reg2, obj2
    const float* cls0 = (const float*)d_in[0];
    const float* reg0 = (const float*)d_in[1];
    const float* obj0 = (const float*)d_in[2];
    const float* cls1 = (const float*)d_in[3];
    const float* reg1 = (const float*)d_in[4];
    const float* obj1 = (const float*)d_in[5];
    const float* cls2 = (const float*)d_in[6];
    const float* reg2 = (const float*)d_in[7];
    const float* obj2 = (const float*)d_in[8];

    // ws layout: boxes | labels | keys
    char* ws = (char*)d_ws;
    size_t nBA = (size_t)BATCH * NA;
    float4* wboxes  = (float4*)ws;
    int*    wlabels = (int*)(ws + nBA * 16);
    uint*   wkeys   = (uint*)(ws + nBA * 20);

    decode_kernel<<<BATCH * DGROUPS, 256, 0, stream>>>(
        cls0, reg0, obj0, cls1, reg1, obj1, cls2, reg2, obj2,
        wboxes, wlabels, wkeys);

    nms_kernel<<<BATCH, NT, 0, stream>>>(wboxes, wlabels, wkeys, (float*)d_out);
}